// Round 10
// baseline (610.202 us; speedup 1.0000x reference)
//
#include <hip/hip_runtime.h>
#include <cstdint>

using f32x4 = __attribute__((ext_vector_type(4))) float;
using s16x8 = __attribute__((ext_vector_type(8))) short;
typedef unsigned short u16;

typedef const __attribute__((address_space(1))) uint32_t* gptr_t;
typedef __attribute__((address_space(3))) uint32_t* lptr_t;

__device__ __forceinline__ u16 f2bf(float f) {
  union { float f; uint32_t u; } v; v.f = f;
  uint32_t r = v.u + 0x7FFFu + ((v.u >> 16) & 1u);  // RNE
  return (u16)(r >> 16);
}
__device__ __forceinline__ float bf2f(u16 b) {
  union { uint32_t u; float f; } v; v.u = ((uint32_t)b) << 16;
  return v.f;
}

// ---------------- k0: normalize prompts -> p_bf (bf16, padded to 1024 rows), ws[0,2MB)
__global__ __launch_bounds__(256) void k_prep_prompts(const float* __restrict__ prompts,
                                                      u16* __restrict__ p_bf) {
  const int r = blockIdx.x;
  const int t = threadIdx.x;
  if (r >= 1000) {
    if (t < 128) {
      s16x8 z = {0, 0, 0, 0, 0, 0, 0, 0};
      ((s16x8*)(p_bf + (size_t)r * 1024))[t] = z;
    }
    return;
  }
  float4 x = ((const float4*)(prompts + (size_t)r * 1024))[t];
  float ss = x.x * x.x + x.y * x.y + x.z * x.z + x.w * x.w;
  #pragma unroll
  for (int off = 32; off; off >>= 1) ss += __shfl_xor(ss, off);
  __shared__ float red[4];
  if ((t & 63) == 0) red[t >> 6] = ss;
  __syncthreads();
  float n = fmaxf(sqrtf(red[0] + red[1] + red[2] + red[3]), 1e-12f);
  float inv = 1.0f / n;
  u16* pb = p_bf + (size_t)r * 1024 + t * 4;
  pb[0] = f2bf(x.x * inv); pb[1] = f2bf(x.y * inv);
  pb[2] = f2bf(x.z * inv); pb[3] = f2bf(x.w * inv);
}

// ---------------- k0b: feat fp32 -> bf16 (scratch at start of MIXED region)
__global__ __launch_bounds__(256) void k_feat(const float* __restrict__ feat,
                                              u16* __restrict__ out) {
  const size_t stride = (size_t)gridDim.x * 256;
  const size_t n4 = 67108864ull / 4;
  for (size_t j = (size_t)blockIdx.x * 256 + threadIdx.x; j < n4; j += stride) {
    float4 x = ((const float4*)feat)[j];
    ushort4 o;
    o.x = f2bf(x.x); o.y = f2bf(x.y); o.z = f2bf(x.z); o.w = f2bf(x.w);
    ((ushort4*)out)[j] = o;
  }
}

// ---------------- k1: bf16 MFMA GEMM, double-buffered LDS, one barrier per K-step.
__global__ __launch_bounds__(256) void k_sims(const u16* __restrict__ A,   // [65536][1024] bf16
                                              const u16* __restrict__ B,   // [1024][1024] bf16
                                              u16* __restrict__ C) {       // [65536][1000] bf16
  __shared__ u16 As[2][128 * 32];
  __shared__ u16 Bs[2][128 * 32];
  const int bid = blockIdx.x;                       // grid 4096 = 8 * 512
  const int lg = (bid & 7) * 512 + (bid >> 3);      // XCD-grouping swizzle (bijective)
  const int bn = lg & 7;
  const int bm = lg >> 3;
  const int t = threadIdx.x;
  const int w = t >> 6, l = t & 63;
  const int wm = (w >> 1) * 64, wn = (w & 1) * 64;
  const int lrow = l & 15, lko = l >> 4;

  f32x4 zero4 = {0.f, 0.f, 0.f, 0.f};
  f32x4 acc[4][4];
  #pragma unroll
  for (int i = 0; i < 4; i++)
    #pragma unroll
    for (int j = 0; j < 4; j++) acc[i][j] = zero4;

  const int srow = t >> 2;          // 0..63
  const int scol = (t & 3) * 8;     // 0,8,16,24
  const u16* gA = A + (size_t)(bm * 128 + srow) * 1024 + scol;
  const u16* gB = B + (size_t)(bn * 128 + srow) * 1024 + scol;

  #pragma unroll
  for (int i = 0; i < 2; i++) {
    __builtin_amdgcn_global_load_lds((gptr_t)(gA + (size_t)i * 64 * 1024),
                                     (lptr_t)&As[0][(i * 64 + srow) * 32 + scol], 16, 0, 0);
    __builtin_amdgcn_global_load_lds((gptr_t)(gB + (size_t)i * 64 * 1024),
                                     (lptr_t)&Bs[0][(i * 64 + srow) * 32 + scol], 16, 0, 0);
  }
  __syncthreads();  // tile 0 staged & visible

  for (int kt = 0; kt < 32; ++kt) {
    const int cur = kt & 1;
    if (kt < 31) {                  // stage next tile into the other buffer
      const int nk = (kt + 1) * 32;
      #pragma unroll
      for (int i = 0; i < 2; i++) {
        __builtin_amdgcn_global_load_lds((gptr_t)(gA + (size_t)i * 64 * 1024 + nk),
                                         (lptr_t)&As[cur ^ 1][(i * 64 + srow) * 32 + scol], 16, 0, 0);
        __builtin_amdgcn_global_load_lds((gptr_t)(gB + (size_t)i * 64 * 1024 + nk),
                                         (lptr_t)&Bs[cur ^ 1][(i * 64 + srow) * 32 + scol], 16, 0, 0);
      }
    }
    s16x8 a[4], b[4];
    #pragma unroll
    for (int mi = 0; mi < 4; mi++) a[mi] = *(const s16x8*)&As[cur][(wm + mi * 16 + lrow) * 32 + lko * 8];
    #pragma unroll
    for (int ni = 0; ni < 4; ni++) b[ni] = *(const s16x8*)&Bs[cur][(wn + ni * 16 + lrow) * 32 + lko * 8];
    #pragma unroll
    for (int mi = 0; mi < 4; mi++)
      #pragma unroll
      for (int ni = 0; ni < 4; ni++)
        acc[mi][ni] = __builtin_amdgcn_mfma_f32_16x16x32_bf16(a[mi], b[ni], acc[mi][ni], 0, 0, 0);
    __syncthreads();
  }
  const int rbase = (l >> 4) * 4;
  #pragma unroll
  for (int mi = 0; mi < 4; mi++)
    #pragma unroll
    for (int ni = 0; ni < 4; ni++) {
      int gcol = bn * 128 + wn + ni * 16 + lrow;
      if (gcol >= 1000) continue;
      #pragma unroll
      for (int j = 0; j < 4; j++) {
        int grow = bm * 128 + wm + mi * 16 + rbase + j;
        C[(size_t)grow * 1000 + gcol] = f2bf(acc[mi][ni][j]);
      }
    }
}

// ---------------- k2: lean screen + serial exact rescore; writes ONLY resc/resw (1 MB).
// Round-8-proven structure; feat loads issued before screen VALU (latency overlap).
__global__ __launch_bounds__(256) void k_topk(const float* __restrict__ feat,
                                              const float* __restrict__ prompts,
                                              const u16* __restrict__ sims,
                                              int2* __restrict__ resc,
                                              float2* __restrict__ resw) {
  const int l = threadIdx.x & 63;
  const int row = blockIdx.x * 4 + (threadIdx.x >> 6);
  const u16* srow = sims + (size_t)row * 1000;
  const float NEG = -3.0e38f;
  // issue sims loads (paired u32; slot jj holds col 2l + 128*(jj>>1) + (jj&1))
  float s[16];
  #pragma unroll
  for (int j = 0; j < 8; j++) {
    int c = 2 * l + 128 * j;
    if (c + 1 < 1000) {
      uint32_t v = *(const uint32_t*)(srow + c);
      s[2 * j] = bf2f((u16)(v & 0xFFFFu));
      s[2 * j + 1] = bf2f((u16)(v >> 16));
    } else {
      s[2 * j] = (c < 1000) ? bf2f(srow[c]) : NEG;
      s[2 * j + 1] = NEG;
    }
  }
  // issue feat loads EARLY (independent of screen; overlaps sims latency + screen VALU)
  const int base = l * 16;
  float q[16];
  const float4* fr = (const float4*)(feat + (size_t)row * 1024 + base);
  #pragma unroll
  for (int g = 0; g < 4; g++) {
    float4 x = fr[g];
    q[g * 4 + 0] = x.x; q[g * 4 + 1] = x.y; q[g * 4 + 2] = x.z; q[g * 4 + 3] = x.w;
  }
  // screen: per-lane top-2, wave butterfly
  float a1 = NEG, a2 = NEG;
  #pragma unroll
  for (int j = 0; j < 16; j++) {
    float v = s[j];
    bool g1 = v > a1;
    a2 = g1 ? a1 : fmaxf(a2, v);
    a1 = g1 ? v : a1;
  }
  #pragma unroll
  for (int off = 32; off; off >>= 1) {
    float b1 = __shfl_xor(a1, off), b2 = __shfl_xor(a2, off);
    float m1 = fmaxf(a1, b1);
    float m2 = fmaxf(fminf(a1, b1), fmaxf(a2, b2));
    a1 = m1; a2 = m2;
  }
  const float T = a2 - 0.25f;   // stored-scale margin (round-8 analysis)
  uint32_t mask = 0;
  #pragma unroll
  for (int j = 0; j < 16; j++) {
    int c = 2 * l + 128 * (j >> 1) + (j & 1);
    if (c < 1000 && s[j] >= T) mask |= (1u << j);
  }
  // row norm
  float qq = 0.f;
  #pragma unroll
  for (int e = 0; e < 16; e++) qq += q[e] * q[e];
  #pragma unroll
  for (int off = 32; off; off >>= 1) qq += __shfl_xor(qq, off);
  float rn = 1.0f / fmaxf(sqrtf(qq), 1e-12f);
  // serial survivor loop: exact fp32 rescore, running top-2 (lower-index tie-break)
  float s1 = NEG, s2 = NEG;
  int c1 = 0x40000000, c2 = 0x40000000;
  while (true) {
    unsigned long long act = __ballot(mask != 0);
    if (!act) break;
    int ln = (int)__ffsll(act) - 1;
    int fj = __ffs(mask) - 1;
    int myc = 2 * l + 128 * ((fj >> 1) & 7) + (fj & 1);
    int bc = __shfl(myc, ln);
    if (l == ln) mask &= (mask - 1);
    bc = (bc < 1000) ? bc : 999;
    const float4* pr = (const float4*)(prompts + (size_t)bc * 1024 + base);
    float d = 0.f, nn = 0.f;
    #pragma unroll
    for (int g = 0; g < 4; g++) {
      float4 x = pr[g];
      d += q[g * 4 + 0] * x.x; d += q[g * 4 + 1] * x.y;
      d += q[g * 4 + 2] * x.z; d += q[g * 4 + 3] * x.w;
      nn += x.x * x.x + x.y * x.y + x.z * x.z + x.w * x.w;
    }
    #pragma unroll
    for (int off = 32; off; off >>= 1) {
      d += __shfl_xor(d, off);
      nn += __shfl_xor(nn, off);
    }
    float sc = d * rn / fmaxf(sqrtf(nn), 1e-12f);
    bool b1w = (sc > s1) || (sc == s1 && bc < c1);
    bool b2w = (sc > s2) || (sc == s2 && bc < c2);
    if (b1w) { s2 = s1; c2 = c1; s1 = sc; c1 = bc; }
    else if (b2w) { s2 = sc; c2 = bc; }
  }
  float e = expf(fminf(s2 - s1, 0.0f) * (1.0f / 0.07f));  // (0,1]
  float w1 = 1.0f / (1.0f + e);
  float w2 = e / (1.0f + e);
  if (l == 0) {
    resc[row] = make_int2(c1, c2);
    resw[row] = make_float2(w1, w2);
  }
}

// ---------------- k3: streaming writer for BOTH outputs (one block per row, ~6 TB/s)
__global__ __launch_bounds__(256) void k_out(const float* __restrict__ prompts,
                                             const int2* __restrict__ resc,
                                             const float2* __restrict__ resw,
                                             float* __restrict__ mixed,
                                             float* __restrict__ probs) {
  const int row = blockIdx.x;
  const int t = threadIdx.x;
  int2 cc = resc[row];
  float2 ww = resw[row];
  // mixed row: 256 x float4
  float4 a = ((const float4*)(prompts + (size_t)cc.x * 1024))[t];
  float4 b = ((const float4*)(prompts + (size_t)cc.y * 1024))[t];
  float4 o;
  o.x = ww.x * a.x + ww.y * b.x;
  o.y = ww.x * a.y + ww.y * b.y;
  o.z = ww.x * a.z + ww.y * b.z;
  o.w = ww.x * a.w + ww.y * b.w;
  ((float4*)(mixed + (size_t)row * 1024))[t] = o;
  // probs row: 250 x float4 (zeros + two weights)
  if (t < 250) {
    const int base = t * 4;
    float4 z;
    z.x = (base + 0 == cc.x) ? ww.x : ((base + 0 == cc.y) ? ww.y : 0.0f);
    z.y = (base + 1 == cc.x) ? ww.x : ((base + 1 == cc.y) ? ww.y : 0.0f);
    z.z = (base + 2 == cc.x) ? ww.x : ((base + 2 == cc.y) ? ww.y : 0.0f);
    z.w = (base + 3 == cc.x) ? ww.x : ((base + 3 == cc.y) ? ww.y : 0.0f);
    ((float4*)(probs + (size_t)row * 1000))[t] = z;
  }
}

extern "C" void kernel_launch(void* const* d_in, const int* in_sizes, int n_in,
                              void* d_out, int out_size, void* d_ws, size_t ws_size,
                              hipStream_t stream) {
  int fi = 0, pi = 1;
  for (int i = 0; i < n_in; i++) {
    if (in_sizes[i] == 67108864) fi = i;
    else if (in_sizes[i] == 1024000) pi = i;
  }
  const float* feat = (const float*)d_in[fi];
  const float* prompts = (const float*)d_in[pi];

  float* mixed = (float*)d_out;                 // [65536*1024] f32 (output 0)
  float* probs = mixed + 67108864ull;           // [65536*1000] f32 (output 1)

  // ws: [0,2MB) p_bf; [2,2.5MB) resc; [2.5,3MB) resw; [3MB,...) sims (big-ws path)
  u16* p_bf = (u16*)d_ws;
  int2* resc = (int2*)((char*)d_ws + (2ull << 20));
  float2* resw = (float2*)((char*)d_ws + (2ull << 20) + (512ull << 10));

  // scratch: feat_bf at start of MIXED region (dead before k_out writes mixed).
  // sims: in ws if it fits, else start of PROBS region (dead before k_out writes probs).
  u16* feat_bf = (u16*)mixed;
  const bool big_ws = ws_size >= (1ull << 27);
  u16* sims = big_ws ? (u16*)((char*)d_ws + (3ull << 20)) : (u16*)probs;

  hipLaunchKernelGGL(k_prep_prompts, dim3(1024), dim3(256), 0, stream, prompts, p_bf);
  hipLaunchKernelGGL(k_feat, dim3(2048), dim3(256), 0, stream, feat, feat_bf);
  hipLaunchKernelGGL(k_sims, dim3(4096), dim3(256), 0, stream, feat_bf, p_bf, sims);
  hipLaunchKernelGGL(k_topk, dim3(16384), dim3(256), 0, stream, feat, prompts, sims, resc, resw);
  hipLaunchKernelGGL(k_out, dim3(65536), dim3(256), 0, stream, prompts, resc, resw, mixed, probs);
}

// Round 11
// 573.023 us; speedup vs baseline: 1.0649x; 1.0649x over previous
//
#include <hip/hip_runtime.h>
#include <cstdint>

using f32x4 = __attribute__((ext_vector_type(4))) float;
using s16x8 = __attribute__((ext_vector_type(8))) short;
typedef unsigned short u16;

typedef const __attribute__((address_space(1))) uint32_t* gptr_t;
typedef __attribute__((address_space(3))) uint32_t* lptr_t;

__device__ __forceinline__ u16 f2bf(float f) {
  union { float f; uint32_t u; } v; v.f = f;
  uint32_t r = v.u + 0x7FFFu + ((v.u >> 16) & 1u);  // RNE
  return (u16)(r >> 16);
}
__device__ __forceinline__ float bf2f(u16 b) {
  union { uint32_t u; float f; } v; v.u = ((uint32_t)b) << 16;
  return v.f;
}

// ---------------- k0: normalize prompts -> p_bf (bf16, padded to 1024 rows), ws[0,2MB)
__global__ __launch_bounds__(256) void k_prep_prompts(const float* __restrict__ prompts,
                                                      u16* __restrict__ p_bf) {
  const int r = blockIdx.x;
  const int t = threadIdx.x;
  if (r >= 1000) {
    if (t < 128) {
      s16x8 z = {0, 0, 0, 0, 0, 0, 0, 0};
      ((s16x8*)(p_bf + (size_t)r * 1024))[t] = z;
    }
    return;
  }
  float4 x = ((const float4*)(prompts + (size_t)r * 1024))[t];
  float ss = x.x * x.x + x.y * x.y + x.z * x.z + x.w * x.w;
  #pragma unroll
  for (int off = 32; off; off >>= 1) ss += __shfl_xor(ss, off);
  __shared__ float red[4];
  if ((t & 63) == 0) red[t >> 6] = ss;
  __syncthreads();
  float n = fmaxf(sqrtf(red[0] + red[1] + red[2] + red[3]), 1e-12f);
  float inv = 1.0f / n;
  u16* pb = p_bf + (size_t)r * 1024 + t * 4;
  pb[0] = f2bf(x.x * inv); pb[1] = f2bf(x.y * inv);
  pb[2] = f2bf(x.z * inv); pb[3] = f2bf(x.w * inv);
}

// ---------------- k0b: feat fp32 -> bf16 (scratch at start of PROBS region)
__global__ __launch_bounds__(256) void k_feat(const float* __restrict__ feat,
                                              u16* __restrict__ out) {
  const size_t stride = (size_t)gridDim.x * 256;
  const size_t n4 = 67108864ull / 4;
  for (size_t j = (size_t)blockIdx.x * 256 + threadIdx.x; j < n4; j += stride) {
    float4 x = ((const float4*)feat)[j];
    ushort4 o;
    o.x = f2bf(x.x); o.y = f2bf(x.y); o.z = f2bf(x.z); o.w = f2bf(x.w);
    ((ushort4*)out)[j] = o;
  }
}

// ---------------- k1: bf16 MFMA GEMM, double-buffered LDS, one barrier per K-step.
__global__ __launch_bounds__(256) void k_sims(const u16* __restrict__ A,   // [65536][1024] bf16
                                              const u16* __restrict__ B,   // [1024][1024] bf16
                                              u16* __restrict__ C) {       // [65536][1000] bf16
  __shared__ u16 As[2][128 * 32];
  __shared__ u16 Bs[2][128 * 32];
  const int bid = blockIdx.x;                       // grid 4096 = 8 * 512
  const int lg = (bid & 7) * 512 + (bid >> 3);      // XCD-grouping swizzle (bijective)
  const int bn = lg & 7;
  const int bm = lg >> 3;
  const int t = threadIdx.x;
  const int w = t >> 6, l = t & 63;
  const int wm = (w >> 1) * 64, wn = (w & 1) * 64;
  const int lrow = l & 15, lko = l >> 4;

  f32x4 zero4 = {0.f, 0.f, 0.f, 0.f};
  f32x4 acc[4][4];
  #pragma unroll
  for (int i = 0; i < 4; i++)
    #pragma unroll
    for (int j = 0; j < 4; j++) acc[i][j] = zero4;

  const int srow = t >> 2;          // 0..63
  const int scol = (t & 3) * 8;     // 0,8,16,24
  const u16* gA = A + (size_t)(bm * 128 + srow) * 1024 + scol;
  const u16* gB = B + (size_t)(bn * 128 + srow) * 1024 + scol;

  #pragma unroll
  for (int i = 0; i < 2; i++) {
    __builtin_amdgcn_global_load_lds((gptr_t)(gA + (size_t)i * 64 * 1024),
                                     (lptr_t)&As[0][(i * 64 + srow) * 32 + scol], 16, 0, 0);
    __builtin_amdgcn_global_load_lds((gptr_t)(gB + (size_t)i * 64 * 1024),
                                     (lptr_t)&Bs[0][(i * 64 + srow) * 32 + scol], 16, 0, 0);
  }
  __syncthreads();  // tile 0 staged & visible

  for (int kt = 0; kt < 32; ++kt) {
    const int cur = kt & 1;
    if (kt < 31) {
      const int nk = (kt + 1) * 32;
      #pragma unroll
      for (int i = 0; i < 2; i++) {
        __builtin_amdgcn_global_load_lds((gptr_t)(gA + (size_t)i * 64 * 1024 + nk),
                                         (lptr_t)&As[cur ^ 1][(i * 64 + srow) * 32 + scol], 16, 0, 0);
        __builtin_amdgcn_global_load_lds((gptr_t)(gB + (size_t)i * 64 * 1024 + nk),
                                         (lptr_t)&Bs[cur ^ 1][(i * 64 + srow) * 32 + scol], 16, 0, 0);
      }
    }
    s16x8 a[4], b[4];
    #pragma unroll
    for (int mi = 0; mi < 4; mi++) a[mi] = *(const s16x8*)&As[cur][(wm + mi * 16 + lrow) * 32 + lko * 8];
    #pragma unroll
    for (int ni = 0; ni < 4; ni++) b[ni] = *(const s16x8*)&Bs[cur][(wn + ni * 16 + lrow) * 32 + lko * 8];
    #pragma unroll
    for (int mi = 0; mi < 4; mi++)
      #pragma unroll
      for (int ni = 0; ni < 4; ni++)
        acc[mi][ni] = __builtin_amdgcn_mfma_f32_16x16x32_bf16(a[mi], b[ni], acc[mi][ni], 0, 0, 0);
    __syncthreads();
  }
  const int rbase = (l >> 4) * 4;
  #pragma unroll
  for (int mi = 0; mi < 4; mi++)
    #pragma unroll
    for (int ni = 0; ni < 4; ni++) {
      int gcol = bn * 128 + wn + ni * 16 + lrow;
      if (gcol >= 1000) continue;
      #pragma unroll
      for (int j = 0; j < 4; j++) {
        int grow = bm * 128 + wm + mi * 16 + rbase + j;
        C[(size_t)grow * 1000 + gcol] = f2bf(acc[mi][ni][j]);
      }
    }
}

// ---------------- k2: TWO rows per wave — screen + merged survivor rescore + inline probs.
// Round-8 proven numerics; 2-row MLP doubles independent work at every latency stall.
__global__ __launch_bounds__(256) void k_topk(const float* __restrict__ feat,
                                              const float* __restrict__ prompts,
                                              const u16* __restrict__ sims,
                                              int2* __restrict__ resc,
                                              float2* __restrict__ resw,
                                              float* __restrict__ probs) {
  const int l = threadIdx.x & 63;
  const int wid = threadIdx.x >> 6;
  const int rowA = blockIdx.x * 8 + wid * 2;
  const int rowB = rowA + 1;
  const float NEG = -3.0e38f;
  const u16* srA = sims + (size_t)rowA * 1000;
  const u16* srB = sims + (size_t)rowB * 1000;
  // ---- sims loads, both rows (32 u32 loads issued together)
  float sA[16], sB[16];
  #pragma unroll
  for (int j = 0; j < 8; j++) {
    int c = 2 * l + 128 * j;
    if (c + 1 < 1000) {
      uint32_t vA = *(const uint32_t*)(srA + c);
      uint32_t vB = *(const uint32_t*)(srB + c);
      sA[2 * j] = bf2f((u16)(vA & 0xFFFFu)); sA[2 * j + 1] = bf2f((u16)(vA >> 16));
      sB[2 * j] = bf2f((u16)(vB & 0xFFFFu)); sB[2 * j + 1] = bf2f((u16)(vB >> 16));
    } else {
      sA[2 * j] = (c < 1000) ? bf2f(srA[c]) : NEG; sA[2 * j + 1] = NEG;
      sB[2 * j] = (c < 1000) ? bf2f(srB[c]) : NEG; sB[2 * j + 1] = NEG;
    }
  }
  // ---- screens (independent chains, back-to-back)
  float a1A = NEG, a2A = NEG, a1B = NEG, a2B = NEG;
  #pragma unroll
  for (int j = 0; j < 16; j++) {
    float vA = sA[j], vB = sB[j];
    bool gA = vA > a1A;
    a2A = gA ? a1A : fmaxf(a2A, vA); a1A = gA ? vA : a1A;
    bool gB = vB > a1B;
    a2B = gB ? a1B : fmaxf(a2B, vB); a1B = gB ? vB : a1B;
  }
  #pragma unroll
  for (int off = 32; off; off >>= 1) {
    float b1 = __shfl_xor(a1A, off), b2 = __shfl_xor(a2A, off);
    float m1 = fmaxf(a1A, b1), m2 = fmaxf(fminf(a1A, b1), fmaxf(a2A, b2));
    a1A = m1; a2A = m2;
    float d1 = __shfl_xor(a1B, off), d2 = __shfl_xor(a2B, off);
    float n1 = fmaxf(a1B, d1), n2 = fmaxf(fminf(a1B, d1), fmaxf(a2B, d2));
    a1B = n1; a2B = n2;
  }
  const float TA = a2A - 0.25f, TB = a2B - 0.25f;  // stored-scale margin (round-8 analysis)
  uint32_t maskA = 0, maskB = 0;
  #pragma unroll
  for (int j = 0; j < 16; j++) {
    int c = 2 * l + 128 * (j >> 1) + (j & 1);
    if (c < 1000) {
      if (sA[j] >= TA) maskA |= (1u << j);
      if (sB[j] >= TB) maskB |= (1u << j);
    }
  }
  // ---- feat rows + norms
  const int base = l * 16;
  float qA[16], qB[16];
  const float4* frA = (const float4*)(feat + (size_t)rowA * 1024 + base);
  const float4* frB = (const float4*)(feat + (size_t)rowB * 1024 + base);
  #pragma unroll
  for (int g = 0; g < 4; g++) {
    float4 x = frA[g], y = frB[g];
    qA[g * 4 + 0] = x.x; qA[g * 4 + 1] = x.y; qA[g * 4 + 2] = x.z; qA[g * 4 + 3] = x.w;
    qB[g * 4 + 0] = y.x; qB[g * 4 + 1] = y.y; qB[g * 4 + 2] = y.z; qB[g * 4 + 3] = y.w;
  }
  float qqA = 0.f, qqB = 0.f;
  #pragma unroll
  for (int e = 0; e < 16; e++) { qqA += qA[e] * qA[e]; qqB += qB[e] * qB[e]; }
  #pragma unroll
  for (int off = 32; off; off >>= 1) {
    qqA += __shfl_xor(qqA, off);
    qqB += __shfl_xor(qqB, off);
  }
  float rnA = 1.0f / fmaxf(sqrtf(qqA), 1e-12f);
  float rnB = 1.0f / fmaxf(sqrtf(qqB), 1e-12f);
  // ---- merged survivor loop: one candidate per row per iteration (independent chains)
  float s1A = NEG, s2A = NEG, s1B = NEG, s2B = NEG;
  int c1A = 0x40000000, c2A = 0x40000000, c1B = 0x40000000, c2B = 0x40000000;
  while (true) {
    unsigned long long actA = __ballot(maskA != 0);
    unsigned long long actB = __ballot(maskB != 0);
    if (!actA && !actB) break;
    int bcA = -1, bcB = -1;
    if (actA) {
      int ln = (int)__ffsll(actA) - 1;
      int fj = __ffs(maskA) - 1;
      int myc = 2 * l + 128 * ((fj >> 1) & 7) + (fj & 1);
      bcA = __shfl(myc, ln);
      if (l == ln) maskA &= (maskA - 1);
      bcA = (bcA < 1000) ? bcA : 999;
    }
    if (actB) {
      int ln = (int)__ffsll(actB) - 1;
      int fj = __ffs(maskB) - 1;
      int myc = 2 * l + 128 * ((fj >> 1) & 7) + (fj & 1);
      bcB = __shfl(myc, ln);
      if (l == ln) maskB &= (maskB - 1);
      bcB = (bcB < 1000) ? bcB : 999;
    }
    float dA = 0.f, nnA = 0.f, dB = 0.f, nnB = 0.f;
    if (bcA >= 0) {   // wave-uniform branch
      const float4* pr = (const float4*)(prompts + (size_t)bcA * 1024 + base);
      #pragma unroll
      for (int g = 0; g < 4; g++) {
        float4 x = pr[g];
        dA += qA[g * 4 + 0] * x.x; dA += qA[g * 4 + 1] * x.y;
        dA += qA[g * 4 + 2] * x.z; dA += qA[g * 4 + 3] * x.w;
        nnA += x.x * x.x + x.y * x.y + x.z * x.z + x.w * x.w;
      }
    }
    if (bcB >= 0) {   // wave-uniform branch
      const float4* pr = (const float4*)(prompts + (size_t)bcB * 1024 + base);
      #pragma unroll
      for (int g = 0; g < 4; g++) {
        float4 x = pr[g];
        dB += qB[g * 4 + 0] * x.x; dB += qB[g * 4 + 1] * x.y;
        dB += qB[g * 4 + 2] * x.z; dB += qB[g * 4 + 3] * x.w;
        nnB += x.x * x.x + x.y * x.y + x.z * x.z + x.w * x.w;
      }
    }
    #pragma unroll
    for (int off = 32; off; off >>= 1) {
      dA += __shfl_xor(dA, off);  nnA += __shfl_xor(nnA, off);
      dB += __shfl_xor(dB, off);  nnB += __shfl_xor(nnB, off);
    }
    if (bcA >= 0) {
      float sc = dA * rnA / fmaxf(sqrtf(nnA), 1e-12f);
      bool b1 = (sc > s1A) || (sc == s1A && bcA < c1A);
      bool b2 = (sc > s2A) || (sc == s2A && bcA < c2A);
      if (b1) { s2A = s1A; c2A = c1A; s1A = sc; c1A = bcA; }
      else if (b2) { s2A = sc; c2A = bcA; }
    }
    if (bcB >= 0) {
      float sc = dB * rnB / fmaxf(sqrtf(nnB), 1e-12f);
      bool b1 = (sc > s1B) || (sc == s1B && bcB < c1B);
      bool b2 = (sc > s2B) || (sc == s2B && bcB < c2B);
      if (b1) { s2B = s1B; c2B = c1B; s1B = sc; c1B = bcB; }
      else if (b2) { s2B = sc; c2B = bcB; }
    }
  }
  float eA = expf(fminf(s2A - s1A, 0.0f) * (1.0f / 0.07f));
  float w1A = 1.0f / (1.0f + eA), w2A = eA / (1.0f + eA);
  float eB = expf(fminf(s2B - s1B, 0.0f) * (1.0f / 0.07f));
  float w1B = 1.0f / (1.0f + eB), w2B = eB / (1.0f + eB);
  // ---- inline probs writes (overwrites dead feat_bf scratch; row-exclusive)
  float* prA = probs + (size_t)rowA * 1000;
  float* prB = probs + (size_t)rowB * 1000;
  #pragma unroll
  for (int j = 0; j < 16; j++) {
    int c = l + 64 * j;
    if (c < 1000) {
      prA[c] = (c == c1A) ? w1A : ((c == c2A) ? w2A : 0.0f);
      prB[c] = (c == c1B) ? w1B : ((c == c2B) ? w2B : 0.0f);
    }
  }
  if (l == 0) {
    resc[rowA] = make_int2(c1A, c2A);
    resw[rowA] = make_float2(w1A, w2A);
    resc[rowB] = make_int2(c1B, c2B);
    resw[rowB] = make_float2(w1B, w2B);
  }
}

// ---------------- k3: mixed = w1*P1 + w2*P2 (one block per row; overwrites dead sims scratch)
__global__ __launch_bounds__(256) void k_write2(const float* __restrict__ prompts,
                                                const int2* __restrict__ resc,
                                                const float2* __restrict__ resw,
                                                float* __restrict__ mixed) {
  const int row = blockIdx.x;
  const int t = threadIdx.x;
  int2 cc = resc[row];
  float2 ww = resw[row];
  float4 a = ((const float4*)(prompts + (size_t)cc.x * 1024))[t];
  float4 b = ((const float4*)(prompts + (size_t)cc.y * 1024))[t];
  float4 o;
  o.x = ww.x * a.x + ww.y * b.x;
  o.y = ww.x * a.y + ww.y * b.y;
  o.z = ww.x * a.z + ww.y * b.z;
  o.w = ww.x * a.w + ww.y * b.w;
  ((float4*)(mixed + (size_t)row * 1024))[t] = o;
}

extern "C" void kernel_launch(void* const* d_in, const int* in_sizes, int n_in,
                              void* d_out, int out_size, void* d_ws, size_t ws_size,
                              hipStream_t stream) {
  int fi = 0, pi = 1;
  for (int i = 0; i < n_in; i++) {
    if (in_sizes[i] == 67108864) fi = i;
    else if (in_sizes[i] == 1024000) pi = i;
  }
  const float* feat = (const float*)d_in[fi];
  const float* prompts = (const float*)d_in[pi];

  float* mixed = (float*)d_out;                 // [65536*1024] f32 (output 0)
  float* probs = mixed + 67108864ull;           // [65536*1000] f32 (output 1)

  // ws: [0,2MB) p_bf; [2,2.5MB) resc; [2.5,3MB) resw
  u16* p_bf = (u16*)d_ws;
  int2* resc = (int2*)((char*)d_ws + (2ull << 20));
  float2* resw = (float2*)((char*)d_ws + (2ull << 20) + (512ull << 10));

  // Round-8 memory plan (row-exclusive aliasing, stream-ordered):
  //   bf16 sims  at start of MIXED region (read by k_topk, overwritten by k_write2)
  //   bf16 feat  at start of PROBS region (read by k_sims, overwritten by k_topk's probs)
  u16* sims = (u16*)mixed;
  u16* feat_bf = (u16*)probs;

  hipLaunchKernelGGL(k_prep_prompts, dim3(1024), dim3(256), 0, stream, prompts, p_bf);
  hipLaunchKernelGGL(k_feat, dim3(2048), dim3(256), 0, stream, feat, feat_bf);
  hipLaunchKernelGGL(k_sims, dim3(4096), dim3(256), 0, stream, feat_bf, p_bf, sims);
  hipLaunchKernelGGL(k_topk, dim3(8192), dim3(256), 0, stream, feat, prompts, sims, resc, resw, probs);
  hipLaunchKernelGGL(k_write2, dim3(65536), dim3(256), 0, stream, prompts, resc, resw, mixed);
}